// Round 8
// baseline (83.661 us; speedup 1.0000x reference)
//
#include <hip/hip_runtime.h>
#include <hip/hip_bf16.h>

typedef unsigned short u16;
typedef __attribute__((ext_vector_type(8))) unsigned short ushort8;
typedef __attribute__((ext_vector_type(4))) unsigned short ushort4_t;
typedef __attribute__((ext_vector_type(8))) short short8;
typedef __attribute__((ext_vector_type(4))) float f32x4;
typedef __attribute__((ext_vector_type(4))) unsigned uint4_t;

#define DEV __device__ __forceinline__

DEV float b2f(u16 u){ return __uint_as_float(((unsigned)u) << 16); }
DEV u16 f2b(float f){
  unsigned x = __float_as_uint(f);
  return (u16)((x + 0x7fffu + ((x >> 16) & 1u)) >> 16);   // RNE
}
DEV unsigned cvtpk(float lo, float hi){   // HW pack: {bf16(lo), bf16(hi)}
  unsigned r;
  asm("v_cvt_pk_bf16_f32 %0, %1, %2" : "=v"(r) : "v"(lo), "v"(hi));
  return r;
}
// (a,b) -> a={a.lo32,b.lo32}, b={a.hi32,b.hi32}   [lane halves]
DEV void pl32swap(unsigned& a, unsigned& b){
  asm("v_permlane32_swap_b32 %0, %1" : "+v"(a), "+v"(b));
}
// (a,b) -> a[16:31]<->b[0:15], a[48:63]<->b[32:47]
DEV void pl16swap(unsigned& a, unsigned& b){
  asm("v_permlane16_swap_b32 %0, %1" : "+v"(a), "+v"(b));
}
DEV short8 ld8(const u16* p){ return __builtin_bit_cast(short8, *(const ushort8*)p); }
DEV short8 ld8s(const u16* p){            // 8B-aligned pair load (stride-36 rows)
  ushort4_t a = *(const ushort4_t*)p;
  ushort4_t b = *(const ushort4_t*)(p + 4);
  ushort8 v;
  #pragma unroll
  for (int j = 0; j < 4; ++j){ v[j] = a[j]; v[j+4] = b[j]; }
  return __builtin_bit_cast(short8, v);
}
DEV f32x4 mfma(short8 a, short8 b, f32x4 c){
  return __builtin_amdgcn_mfma_f32_16x16x32_bf16(a, b, c, 0, 0, 0);
}
DEV float fast_tanh(float x){
  float e = __expf(2.f * x);
  return 1.f - 2.f / (e + 1.f);
}
DEV unsigned pk2(float lo, float hi){
  return (unsigned)f2b(lo) | ((unsigned)f2b(hi) << 16);
}

// ---- prep kernel: blocks 0..383 = weight transpose fp32->bf16; 384..1407 = LN
__global__ __launch_bounds__(256) void prep_k(
    const float* __restrict__ w1, const float* __restrict__ w2,
    const float* __restrict__ w3, const float* __restrict__ w4,
    const float* __restrict__ w5, const float* __restrict__ w6,
    u16* __restrict__ ws,
    const float* __restrict__ xg, const float* __restrict__ gg,
    const float* __restrict__ bgm, u16* __restrict__ ng)
{
  __shared__ u16 tile[64][72];
  const int bid = blockIdx.x;
  if (bid < 384) {
    const int z = bid / 64, rem = bid % 64, by = rem / 8, bx = rem % 8;
    const float* w; u16* wt; int K;
    switch (z) {
      case 0:  w = w1; wt = ws;          K = 256; break;
      case 1:  w = w2; wt = ws + 131072; K = 512; break;
      case 2:  w = w3; wt = ws + 393216; K = 256; break;
      case 3:  w = w4; wt = ws + 524288; K = 512; break;
      case 4:  w = w5; wt = ws + 786432; K = 256; break;
      default: w = w6; wt = ws + 917504; K = 512; break;
    }
    int k0 = by * 64;
    if (k0 >= K) return;                      // uniform per block
    int n0 = bx * 64;
    int t = threadIdx.x;
    int r = t >> 2, c0 = (t & 3) * 16;
    const float* src = w + (size_t)(k0 + r) * 512 + n0 + c0;
    #pragma unroll
    for (int jj = 0; jj < 4; ++jj) {
      float4 v = *(const float4*)(src + jj * 4);
      unsigned* tp = (unsigned*)&tile[r][c0 + jj*4];
      tp[0] = cvtpk(v.x, v.y);
      tp[1] = cvtpk(v.z, v.w);
    }
    __syncthreads();
    ushort8 o0, o1;
    #pragma unroll
    for (int j = 0; j < 8; ++j) { o0[j] = tile[c0 + j][r]; o1[j] = tile[c0 + 8 + j][r]; }
    u16* dst = wt + (size_t)(n0 + r) * K + k0 + c0;
    *(ushort8*)dst       = o0;
    *(ushort8*)(dst + 8) = o1;
  } else {
    const int lb = bid - 384;
    int row = lb * 8 + (threadIdx.x >> 5);
    int l32 = threadIdx.x & 31;
    const float* xr = xg + (size_t)row*256 + l32*8;
    float xf[8];
    #pragma unroll
    for (int j = 0; j < 8; j += 4) {
      float4 v = *(const float4*)(xr + j);
      xf[j] = v.x; xf[j+1] = v.y; xf[j+2] = v.z; xf[j+3] = v.w;
    }
    float s = 0.f, ss = 0.f;
    #pragma unroll
    for (int j = 0; j < 8; ++j){ s += xf[j]; ss += xf[j]*xf[j]; }
    #pragma unroll
    for (int m = 1; m < 32; m <<= 1){ s += __shfl_xor(s, m); ss += __shfl_xor(ss, m); }
    float mean = s * (1.f/256.f);
    float var  = ss * (1.f/256.f) - mean*mean;
    float rs   = rsqrtf(var + 1e-5f);
    float r8[8];
    #pragma unroll
    for (int j = 0; j < 8; j += 4) {
      float4 gv = *(const float4*)(gg  + l32*8 + j);
      float4 bv = *(const float4*)(bgm + l32*8 + j);
      r8[j]   = (xf[j]   - mean)*rs*gv.x + bv.x;
      r8[j+1] = (xf[j+1] - mean)*rs*gv.y + bv.y;
      r8[j+2] = (xf[j+2] - mean)*rs*gv.z + bv.z;
      r8[j+3] = (xf[j+3] - mean)*rs*gv.w + bv.w;
    }
    uint4_t o;
    o[0] = cvtpk(r8[0], r8[1]); o[1] = cvtpk(r8[2], r8[3]);
    o[2] = cvtpk(r8[4], r8[5]); o[3] = cvtpk(r8[6], r8[7]);
    *(uint4_t*)(ng + (size_t)row*256 + l32*8) = o;
  }
}

// ---- batched GEMM: C[8192,512] = act(A[8192,KA] @ Wt[512,KA]^T + bias) ----
// grid (64, 4, 3=z-branch); 512 thr = 8 waves (2M x 4N); tile 128x128, BK=32
template<int NS, int ACT>   // KA = NS*32; ACT: 1 relu, 2 none, 3 per-z (tanh,tanh,relu)
__global__ __launch_bounds__(512, 4) void gemm_tile(
    const u16* __restrict__ Abase, size_t a_zstride,
    const u16* __restrict__ wst, int w_off0,
    const float* __restrict__ bz0, const float* __restrict__ bz1, const float* __restrict__ bz2,
    u16* __restrict__ Cbase)
{
  constexpr int KA = NS * 32;
  __shared__ __align__(16) u16 sm[20480];   // A dbuf [2][5120] | B dbuf [2][5120]; epilogue C-tile [128][132]
  u16* smA = sm;
  u16* smB = sm + 10240;
  const int z = blockIdx.z;
  const u16* A = Abase + (size_t)z * a_zstride;
  const u16* W = wst + w_off0 + z * 393216;
  const float* bias = (z == 0) ? bz0 : ((z == 1) ? bz1 : bz2);
  u16* C = Cbase + (size_t)z * 4194304;
  const int M0 = blockIdx.x * 128, N0 = blockIdx.y * 128;
  const int tid = threadIdx.x;
  const int wv = tid >> 6, ln = tid & 63, q = ln >> 4, r16 = ln & 15;
  const int m0w = (wv >> 2) * 64, n0w = (wv & 3) * 32;
  const f32x4 Z = {0.f, 0.f, 0.f, 0.f};

  // staging: thread -> (row, 8-el chunk)
  const int srow = tid >> 2, scq = (tid & 3) * 8;
  const u16* gA = A + (size_t)(M0 + srow) * KA + scq;
  const u16* gB = W + (size_t)(N0 + srow) * KA + scq;
  u16* dA = smA + srow * 40 + scq;
  u16* dB = smB + srow * 40 + scq;

  ushort8 rA[2], rB[2];
  rA[0] = *(const ushort8*)gA;
  rB[0] = *(const ushort8*)gB;
  *(ushort8*)dA = rA[0];
  *(ushort8*)dB = rB[0];
  if (NS > 1) { rA[1] = *(const ushort8*)(gA + 32); rB[1] = *(const ushort8*)(gB + 32); }
  __syncthreads();

  f32x4 acc[4][2];
  #pragma unroll
  for (int mf = 0; mf < 4; ++mf){ acc[mf][0] = Z; acc[mf][1] = Z; }

  #pragma unroll
  for (int kk = 0; kk < NS; ++kk) {
    const int cur = kk & 1;
    const u16* bufA = smA + cur * 5120;
    const u16* bufB = smB + cur * 5120;
    short8 aF[4], bF[2];
    #pragma unroll
    for (int mf = 0; mf < 4; ++mf) aF[mf] = ld8(bufA + (m0w + mf*16 + r16)*40 + q*8);
    #pragma unroll
    for (int nf = 0; nf < 2; ++nf) bF[nf] = ld8(bufB + (n0w + nf*16 + r16)*40 + q*8);
    #pragma unroll
    for (int mf = 0; mf < 4; ++mf)
      #pragma unroll
      for (int nf = 0; nf < 2; ++nf)
        acc[mf][nf] = mfma(aF[mf], bF[nf], acc[mf][nf]);
    if (kk + 1 < NS) {
      *(ushort8*)(dA + (cur ^ 1) * 5120) = rA[(kk + 1) & 1];
      *(ushort8*)(dB + (cur ^ 1) * 5120) = rB[(kk + 1) & 1];
    }
    if (kk + 2 < NS) {
      rA[kk & 1] = *(const ushort8*)(gA + (kk + 2) * 32);
      rB[kk & 1] = *(const ushort8*)(gB + (kk + 2) * 32);
    }
    __syncthreads();
  }

  // epilogue: bias + act -> LDS C-tile [128][132] -> coalesced global store
  u16* ct = sm;
  #pragma unroll
  for (int nf = 0; nf < 2; ++nf) {
    int colL = n0w + nf*16 + r16;
    float bs = bias[N0 + colL];
    #pragma unroll
    for (int mf = 0; mf < 4; ++mf)
      #pragma unroll
      for (int i = 0; i < 4; ++i) {
        int row = m0w + mf*16 + q*4 + i;
        float v = acc[mf][nf][i] + bs;
        if (ACT == 1) v = fmaxf(v, 0.f);
        else if (ACT == 3) v = (z == 2) ? fmaxf(v, 0.f) : fast_tanh(v);
        ct[row*132 + colL] = f2b(v);
      }
  }
  __syncthreads();
  #pragma unroll
  for (int j = 0; j < 4; ++j) {
    int row = (tid >> 4) + j*32;
    int cb2 = (tid & 15) * 8;
    ushort8 vv = *(const ushort8*)(ct + row*132 + cb2);
    *(ushort8*)(C + (size_t)(M0 + row)*512 + N0 + cb2) = vv;
  }
}

// ---- attention kernel v2: 2 blocks per window (split g-columns), 512 thr ----
// LDS (u16 els): 62 KB -> 2 blocks/CU
#define AQT2  0       // Qt [512][36]  (18432)
#define AKT2  18432   // Kt-half [256][36] (9216)
#define ABT2  27648   // beta_time fp32 [32][33] (2112 u16)
#define AAT2  29760   // A_time bf16 [32][40] (1280)
#define ASM2_ELS 31040

__global__ __launch_bounds__(512, 4) void attn_k2(
    const u16* __restrict__ QKVg, float* __restrict__ outg)
{
  __shared__ __align__(16) u16 sm[ASM2_ELS];
  const int tid = threadIdx.x;
  const int bid = blockIdx.x;
  const int win = bid >> 1, hb = bid & 1;     // window, column-half
  const int wv = tid >> 6, ln = tid & 63, q = ln >> 4, r16 = ln & 15;
  const f32x4 Z = {0.f, 0.f, 0.f, 0.f};
  const float RS512 = 0.04419417382415922f;   // 1/sqrt(512)
  const float C32L2 = 0.25500526676986233f;   // log2(e)/sqrt(32)
  const u16* Qg = QKVg + (size_t)win * 16384;
  const u16* Kg = QKVg + 4194304 + (size_t)win * 16384;
  const u16* Vg = QKVg + 8388608 + (size_t)win * 16384;

  // ---- PX: QK^T (waves 0-3) || Qt build full [512] (waves 4-7, x2 loop)
  float* btf = (float*)(sm + ABT2);
  if (wv < 4) {
    int mt = wv >> 1, nt = wv & 1;
    f32x4 acc = Z;
    const u16* qb = Qg + (mt*16 + r16)*512;
    const u16* kb = Kg + (nt*16 + r16)*512;
    #pragma unroll
    for (int kk = 0; kk < 16; ++kk)
      acc = mfma(ld8(qb + kk*32 + q*8), ld8(kb + kk*32 + q*8), acc);
    #pragma unroll
    for (int i = 0; i < 4; ++i)
      btf[(mt*16 + q*4 + i)*33 + nt*16 + r16] = acc[i] * RS512;
  } else {
    int t1 = tid - 256;                  // 0..255
    int rp = t1 & 15;                    // rows 2rp, 2rp+1
    unsigned* qt32 = (unsigned*)(sm + AQT2);
    #pragma unroll
    for (int h2 = 0; h2 < 2; ++h2) {
      int cb = (t1 >> 4) * 16 + h2 * 256;  // h-base
      const u16* s0 = Qg + (2*rp)*512 + cb;
      const u16* s1 = s0 + 512;
      ushort8 a0 = *(const ushort8*)s0, a1 = *(const ushort8*)(s0 + 8);
      ushort8 c0v = *(const ushort8*)s1, c1v = *(const ushort8*)(s1 + 8);
      #pragma unroll
      for (int j = 0; j < 8; ++j) {
        qt32[(cb + j)*18 + rp]     = (unsigned)a0[j] | ((unsigned)c0v[j] << 16);
        qt32[(cb + 8 + j)*18 + rp] = (unsigned)a1[j] | ((unsigned)c1v[j] << 16);
      }
    }
  }
  __syncthreads();

  // ---- PY: time softmax (threads 0-255, 8 thr/row) || Kt-half build (threads 256-511)
  if (tid < 256) {
    int row = tid >> 3, t8 = tid & 7;
    int c = t8 * 4;
    float v0 = btf[row*33 + c + 0], v1 = btf[row*33 + c + 1];
    float v2 = btf[row*33 + c + 2], v3 = btf[row*33 + c + 3];
    float m = fmaxf(fmaxf(v0, v1), fmaxf(v2, v3));
    #pragma unroll
    for (int msk = 1; msk < 8; msk <<= 1) m = fmaxf(m, __shfl_xor(m, msk));
    float e0 = __expf(v0 - m), e1 = __expf(v1 - m);
    float e2 = __expf(v2 - m), e3 = __expf(v3 - m);
    float sum = (e0 + e1) + (e2 + e3);
    #pragma unroll
    for (int msk = 1; msk < 8; msk <<= 1) sum += __shfl_xor(sum, msk);
    float inv = 1.f / sum;
    unsigned* at32 = (unsigned*)(sm + AAT2);
    at32[(row*40 + c)/2]     = cvtpk(e0 * inv, e1 * inv);
    at32[(row*40 + c)/2 + 1] = cvtpk(e2 * inv, e3 * inv);
  } else {
    int t1 = tid - 256;                  // 0..255
    int rp = t1 & 15;
    int cb = (t1 >> 4) * 16;             // local col-group 0..240
    const u16* s0 = Kg + (2*rp)*512 + hb*256 + cb;
    const u16* s1 = s0 + 512;
    ushort8 a0 = *(const ushort8*)s0, a1 = *(const ushort8*)(s0 + 8);
    ushort8 c0v = *(const ushort8*)s1, c1v = *(const ushort8*)(s1 + 8);
    unsigned* kt32 = (unsigned*)(sm + AKT2);
    #pragma unroll
    for (int j = 0; j < 8; ++j) {
      kt32[(cb + j)*18 + rp]     = (unsigned)a0[j] | ((unsigned)c0v[j] << 16);
      kt32[(cb + 8 + j)*18 + rp] = (unsigned)a1[j] | ((unsigned)c1v[j] << 16);
    }
  }
  __syncthreads();

  // ---- P6: feature attention (per wave = 32 local cols) + in-register P7
  {
    const int g0 = wv * 32;              // local col base
    f32x4 facc[2][2];
    facc[0][0]=Z; facc[0][1]=Z; facc[1][0]=Z; facc[1][1]=Z;
    float csum[2] = {0.f, 0.f};
    short8 bK[2];                          // K-dim = w = 32, same frags all tiles
    #pragma unroll
    for (int gt = 0; gt < 2; ++gt)
      bK[gt] = ld8s(sm + AKT2 + (g0 + gt*16 + r16)*36 + q*8);

    #pragma unroll 2
    for (int ht = 0; ht < 16; ++ht) {      // h-tiles of 32
      // independent global V loads first (hide L2 latency under softmax VALU)
      short8 aV[2];
      #pragma unroll
      for (int mt = 0; mt < 2; ++mt)
        aV[mt] = ld8(Vg + (mt*16 + r16)*512 + ht*32 + q*8);
      f32x4 sv[2][2];
      #pragma unroll
      for (int smi = 0; smi < 2; ++smi) {
        short8 aQ = ld8s(sm + AQT2 + (ht*32 + smi*16 + r16)*36 + q*8);
        #pragma unroll
        for (int gt = 0; gt < 2; ++gt)
          sv[smi][gt] = mfma(aQ, bK[gt], Z);
      }
      unsigned D[2][4];
      #pragma unroll
      for (int gt = 0; gt < 2; ++gt) {
        float e[2][4];
        #pragma unroll
        for (int smi = 0; smi < 2; ++smi)
          #pragma unroll
          for (int i = 0; i < 4; ++i) {
            float ev = exp2f(sv[smi][gt][i] * C32L2);   // no max-sub: |logit| small
            e[smi][i] = ev;
            csum[gt] += ev;
          }
        #pragma unroll
        for (int k = 0; k < 2; ++k) {
          unsigned w0 = cvtpk(e[0][2*k], e[0][2*k+1]);  // smi=0 pair
          unsigned w1 = cvtpk(e[1][2*k], e[1][2*k+1]);  // smi=1 pair
          pl32swap(w0, w1);
          pl16swap(w0, w1);
          D[gt][k]     = w0;
          D[gt][k + 2] = w1;
        }
      }
      #pragma unroll
      for (int mt = 0; mt < 2; ++mt)
        #pragma unroll
        for (int gt = 0; gt < 2; ++gt) {
          uint4_t dv = {D[gt][0], D[gt][1], D[gt][2], D[gt][3]};
          short8 bE = __builtin_bit_cast(short8, dv);
          facc[mt][gt] = mfma(aV[mt], bE, facc[mt][gt]);
        }
    }
    float inv[2];
    #pragma unroll
    for (int gt = 0; gt < 2; ++gt) {
      float cs = csum[gt];
      cs += __shfl_xor(cs, 16);
      cs += __shfl_xor(cs, 32);
      inv[gt] = 1.f / cs;
    }
    // normalize + redistribute facc (D-layout) -> B-frag layout via permlane
    unsigned F[2][4];
    #pragma unroll
    for (int gt = 0; gt < 2; ++gt) {
      float e0n[4], e1n[4];
      #pragma unroll
      for (int i = 0; i < 4; ++i) {
        e0n[i] = facc[0][gt][i] * inv[gt];
        e1n[i] = facc[1][gt][i] * inv[gt];
      }
      #pragma unroll
      for (int k = 0; k < 2; ++k) {
        unsigned w0 = cvtpk(e0n[2*k], e0n[2*k+1]);      // mt=0 pair
        unsigned w1 = cvtpk(e1n[2*k], e1n[2*k+1]);      // mt=1 pair
        pl32swap(w0, w1);
        pl16swap(w0, w1);
        F[gt][k]     = w0;
        F[gt][k + 2] = w1;
      }
    }
    // ---- P7: out = A_time @ feat (feat fed from registers) ----
    short8 aA0 = ld8(sm + AAT2 + r16*40 + q*8);
    short8 aA1 = ld8(sm + AAT2 + (16 + r16)*40 + q*8);
    #pragma unroll
    for (int gt = 0; gt < 2; ++gt) {
      uint4_t fv = {F[gt][0], F[gt][1], F[gt][2], F[gt][3]};
      short8 bF = __builtin_bit_cast(short8, fv);
      f32x4 o0 = mfma(aA0, bF, Z);
      f32x4 o1 = mfma(aA1, bF, Z);
      #pragma unroll
      for (int i = 0; i < 4; ++i) {
        int gg = hb*256 + g0 + gt*16 + r16;
        outg[(size_t)(win*32 + q*4 + i)*512 + gg]      = o0[i];
        outg[(size_t)(win*32 + 16 + q*4 + i)*512 + gg] = o1[i];
      }
    }
  }
}

// =================== FALLBACK (R4 mega-kernel, unchanged) ===================

#define OFF_V   0
#define OFF_N   16640
#define OFF_T   25088
#define OFF_Q   41728
#define OFF_K   58368
#define OFF_BT  75008
#define OFF_QT  16640
#define OFF_KT  37120
#define OFF_AT  78080
#define OFF_FT  37120
#define SMEM_ELS 79360

template<int ACT>
DEV void mlp_branch(const u16* __restrict__ nl, u16* __restrict__ tl, u16* __restrict__ ol,
                    const u16* __restrict__ wA, const float* __restrict__ bA,
                    const u16* __restrict__ wB, const float* __restrict__ bB,
                    int wv, int q, int r16)
{
  const f32x4 Z = {0.f, 0.f, 0.f, 0.f};
  const int c0 = wv*32 + r16;
  float biasA0 = bA[c0], biasA1 = bA[c0 + 16];
  float biasB0 = bB[c0], biasB1 = bB[c0 + 16];
  {
    const u16* cp0 = wA + (size_t)c0*256 + q*8;
    const u16* cp1 = cp0 + 16*256;
    const u16* a0p = nl + r16 * 264 + q*8;
    const u16* a1p = nl + (16 + r16) * 264 + q*8;
    f32x4 acc[2][2];
    acc[0][0]=Z; acc[0][1]=Z; acc[1][0]=Z; acc[1][1]=Z;
    #pragma unroll
    for (int kk = 0; kk < 8; ++kk) {
      short8 a0 = ld8(a0p + kk*32);
      short8 a1 = ld8(a1p + kk*32);
      short8 b0 = ld8(cp0 + kk*32);
      short8 b1 = ld8(cp1 + kk*32);
      acc[0][0] = mfma(a0, b0, acc[0][0]);
      acc[1][0] = mfma(a1, b0, acc[1][0]);
      acc[0][1] = mfma(a0, b1, acc[0][1]);
      acc[1][1] = mfma(a1, b1, acc[1][1]);
    }
    #pragma unroll
    for (int gt = 0; gt < 2; ++gt) {
      float bias = gt ? biasA1 : biasA0;
      #pragma unroll
      for (int mt = 0; mt < 2; ++mt)
        #pragma unroll
        for (int i = 0; i < 4; ++i) {
          float v = acc[mt][gt][i] + bias;
          v = (ACT == 0) ? fast_tanh(v) : fmaxf(v, 0.f);
          tl[(mt*16 + q*4 + i)*520 + c0 + gt*16] = f2b(v);
        }
    }
  }
  __syncthreads();
  {
    const u16* cp0 = wB + (size_t)c0*512 + q*8;
    const u16* cp1 = cp0 + 16*512;
    const u16* a0p = tl + r16 * 520 + q*8;
    const u16* a1p = tl + (16 + r16) * 520 + q*8;
    f32x4 acc[2][2];
    acc[0][0]=Z; acc[0][1]=Z; acc[1][0]=Z; acc[1][1]=Z;
    #pragma unroll
    for (int kk = 0; kk < 16; ++kk) {
      short8 a0 = ld8(a0p + kk*32);
      short8 a1 = ld8(a1p + kk*32);
      short8 b0 = ld8(cp0 + kk*32);
      short8 b1 = ld8(cp1 + kk*32);
      acc[0][0] = mfma(a0, b0, acc[0][0]);
      acc[1][0] = mfma(a1, b0, acc[1][0]);
      acc[0][1] = mfma(a0, b1, acc[0][1]);
      acc[1][1] = mfma(a1, b1, acc[1][1]);
    }
    #pragma unroll
    for (int gt = 0; gt < 2; ++gt) {
      float bias = gt ? biasB1 : biasB0;
      #pragma unroll
      for (int mt = 0; mt < 2; ++mt)
        #pragma unroll
        for (int i = 0; i < 4; ++i)
          ol[(mt*16 + q*4 + i)*520 + c0 + gt*16] = f2b(acc[mt][gt][i] + bias);
    }
  }
}

__global__ __launch_bounds__(1024) void fused_main(
    const float* __restrict__ xg, const float* __restrict__ gg, const float* __restrict__ bgm,
    const float* __restrict__ b1, const float* __restrict__ b2, const float* __restrict__ b3,
    const float* __restrict__ b4, const float* __restrict__ b5, const float* __restrict__ b6,
    const u16* __restrict__ wst, float* __restrict__ outg)
{
  __shared__ __align__(16) u16 sm[SMEM_ELS];
  const int tid = threadIdx.x;
  const int bid = blockIdx.x;
  const int wv = tid >> 6, ln = tid & 63, q = ln >> 4, r16 = ln & 15;
  const f32x4 Z = {0.f, 0.f, 0.f, 0.f};
  const float RS512 = 0.04419417382415922f;
  const float C32L2 = 0.25500526676986233f;

  {
    int row = tid >> 5, l32 = tid & 31;
    const float* xr = xg + (size_t)(bid*32 + row)*256 + l32*8;
    float xf[8];
    #pragma unroll
    for (int j = 0; j < 8; j += 4) {
      float4 v = *(const float4*)(xr + j);
      xf[j] = v.x; xf[j+1] = v.y; xf[j+2] = v.z; xf[j+3] = v.w;
    }
    float s = 0.f, ss = 0.f;
    #pragma unroll
    for (int j = 0; j < 8; ++j){ s += xf[j]; ss += xf[j]*xf[j]; }
    #pragma unroll
    for (int m = 1; m < 32; m <<= 1){ s += __shfl_xor(s, m); ss += __shfl_xor(ss, m); }
    float mean = s * (1.f/256.f);
    float var  = ss * (1.f/256.f) - mean*mean;
    float rs   = rsqrtf(var + 1e-5f);
    float gf[8], bf[8];
    #pragma unroll
    for (int j = 0; j < 8; j += 4) {
      float4 gv = *(const float4*)(gg  + l32*8 + j);
      float4 bv = *(const float4*)(bgm + l32*8 + j);
      gf[j] = gv.x; gf[j+1] = gv.y; gf[j+2] = gv.z; gf[j+3] = gv.w;
      bf[j] = bv.x; bf[j+1] = bv.y; bf[j+2] = bv.z; bf[j+3] = bv.w;
    }
    ushort8 o0;
    #pragma unroll
    for (int j = 0; j < 8; ++j)
      o0[j] = f2b((xf[j] - mean)*rs*gf[j] + bf[j]);
    *(ushort8*)(sm + OFF_N + row*264 + l32*8) = o0;
  }
  __syncthreads();

  mlp_branch<0>(sm+OFF_N, sm+OFF_T, sm+OFF_Q, wst,          b1, wst + 131072, b2, wv, q, r16);
  __syncthreads();
  mlp_branch<0>(sm+OFF_N, sm+OFF_T, sm+OFF_K, wst + 393216, b3, wst + 524288, b4, wv, q, r16);
  __syncthreads();
  mlp_branch<1>(sm+OFF_N, sm+OFF_T, sm+OFF_V, wst + 786432, b5, wst + 917504, b6, wv, q, r16);
  __syncthreads();

  float* btf = (float*)(sm + OFF_BT);
  if (wv < 4) {
    int mt = wv >> 1, nt = wv & 1;
    f32x4 acc = Z;
    const u16* qb = sm + OFF_Q + (mt*16 + r16)*520;
    const u16* kb = sm + OFF_K + (nt*16 + r16)*520;
    for (int kk = 0; kk < 16; ++kk)
      acc = mfma(ld8(qb + kk*32 + q*8), ld8(kb + kk*32 + q*8), acc);
    #pragma unroll
    for (int i = 0; i < 4; ++i)
      btf[(mt*16 + q*4 + i)*33 + nt*16 + r16] = acc[i] * RS512;
  } else if (wv < 12) {
    int t1 = tid - 256;
    int row = t1 & 31, cb = (t1 >> 5) * 32;
    const u16* src = sm + OFF_Q + row*520 + cb;
    ushort8 v[4];
    #pragma unroll
    for (int jj = 0; jj < 4; ++jj) v[jj] = *(const ushort8*)(src + jj*8);
    #pragma unroll
    for (int jj = 0; jj < 4; ++jj)
      #pragma unroll
      for (int j = 0; j < 8; ++j)
        sm[OFF_QT + (cb + jj*8 + j)*40 + row] = v[jj][j];
  }
  __syncthreads();

  if (tid < 512) {
    int row = tid >> 4, v2 = tid & 15;
    float v0 = btf[row*33 + v2], v1 = btf[row*33 + v2 + 16];
    float m = fmaxf(v0, v1);
    #pragma unroll
    for (int msk = 1; msk < 16; msk <<= 1) m = fmaxf(m, __shfl_xor(m, msk));
    float e0 = __expf(v0 - m), e1 = __expf(v1 - m);
    float sum = e0 + e1;
    #pragma unroll
    for (int msk = 1; msk < 16; msk <<= 1) sum += __shfl_xor(sum, msk);
    float inv = 1.f / sum;
    sm[OFF_AT + row*40 + v2]      = f2b(e0 * inv);
    sm[OFF_AT + row*40 + v2 + 16] = f2b(e1 * inv);
  } else {
    int t2 = tid - 512;
    int row = t2 & 31, cb = (t2 >> 5) * 32;
    const u16* src = sm + OFF_K + row*520 + cb;
    ushort8 v[4];
    #pragma unroll
    for (int jj = 0; jj < 4; ++jj) v[jj] = *(const ushort8*)(src + jj*8);
    #pragma unroll
    for (int jj = 0; jj < 4; ++jj)
      #pragma unroll
      for (int j = 0; j < 8; ++j)
        sm[OFF_KT + (cb + jj*8 + j)*40 + row] = v[jj][j];
  }
  __syncthreads();

  {
    const int g0 = wv * 32;
    const bool hi32 = (ln >= 32);
    const bool qodd = (q & 1);
    f32x4 facc[2][2];
    facc[0][0]=Z; facc[0][1]=Z; facc[1][0]=Z; facc[1][1]=Z;
    float csum[2] = {0.f, 0.f};
    short8 bK[2];
    #pragma unroll
    for (int gt = 0; gt < 2; ++gt)
      bK[gt] = ld8(sm + OFF_KT + (size_t)(g0 + gt*16 + r16)*40 + q*8);

    #pragma unroll 2
    for (int ht = 0; ht < 16; ++ht) {
      f32x4 sv[2][2];
      #pragma unroll
      for (int smi = 0; smi < 2; ++smi) {
        short8 aQ = ld8(sm + OFF_QT + (ht*32 + smi*16 + r16)*40 + q*8);
        #pragma unroll
        for (int gt = 0; gt < 2; ++gt)
          sv[smi][gt] = mfma(aQ, bK[gt], Z);
      }
      unsigned D[2][4];
      #pragma unroll
      for (int gt = 0; gt < 2; ++gt) {
        float e[2][4];
        #pragma unroll
        for (int smi = 0; smi < 2; ++smi)
          #pragma unroll
          for (int i = 0; i < 4; ++i) {
            float ev = exp2f(sv[smi][gt][i] * C32L2);
            e[smi][i] = ev;
            csum[gt] += ev;
          }
        #pragma unroll
        for (int k = 0; k < 2; ++k) {
          unsigned w0 = pk2(e[0][2*k], e[0][2*k+1]);
          unsigned w1 = pk2(e[1][2*k], e[1][2*k+1]);
          unsigned Pw0 = (unsigned)__shfl_xor((int)w0, 32);
          unsigned Pw1 = (unsigned)__shfl_xor((int)w1, 32);
          unsigned x = hi32 ? Pw1 : w0;
          unsigned y = hi32 ? w1 : Pw0;
          unsigned xs = (unsigned)__shfl_xor((int)x, 16);
          unsigned ys = (unsigned)__shfl_xor((int)y, 16);
          D[gt][k]     = qodd ? ys : x;
          D[gt][k + 2] = qodd ? y  : xs;
        }
      }
      #pragma unroll
      for (int mt = 0; mt < 2; ++mt) {
        short8 aV = ld8(sm + OFF_V + (mt*16 + r16)*520 + ht*32 + q*8);
        #pragma unroll
        for (int gt = 0; gt < 2; ++gt) {
          uint4_t dv = {D[gt][0], D[gt][1], D[gt][2], D[gt][3]};
          short8 bE = __builtin_bit_cast(short8, dv);
          facc[mt][gt] = mfma(aV, bE, facc[mt][gt]);
        }
      }
    }
    float inv[2];
    #pragma unroll
    for (int gt = 0; gt < 2; ++gt) {
      float cs = csum[gt];
      cs += __shfl_xor(cs, 16);
      cs += __shfl_xor(cs, 32);
      inv[gt] = 1.f / cs;
    }
    #pragma unroll
    for (int mt = 0; mt < 2; ++mt)
      #pragma unroll
      for (int gt = 0; gt < 2; ++gt)
        #pragma unroll
        for (int i = 0; i < 4; ++i) {
          int w = mt*16 + q*4 + i;
          int g = g0 + gt*16 + r16;
          sm[OFF_FT + g*40 + w] = f2b(facc[mt][gt][i] * inv[gt]);
        }
  }

  {
    const int g0 = wv * 32;
    short8 aA0 = ld8(sm + OFF_AT + r16*40 + q*8);
    short8 aA1 = ld8(sm + OFF_AT + (16 + r16)*40 + q*8);
    #pragma unroll
    for (int gt = 0; gt < 2; ++gt) {
      short8 bF = ld8(sm + OFF_FT + (size_t)(g0 + gt*16 + r16)*40 + q*8);
      f32x4 o0 = mfma(aA0, bF, Z);
      f32x4 o1 = mfma(aA1, bF, Z);
      #pragma unroll
      for (int i = 0; i < 4; ++i) {
        int g = g0 + gt*16 + r16;
        outg[(size_t)(bid*32 + q*4 + i)*512 + g]      = o0[i];
        outg[(size_t)(bid*32 + 16 + q*4 + i)*512 + g] = o1[i];
      }
    }
  }
}

// =================== launch ===================

extern "C" void kernel_launch(void* const* d_in, const int* in_sizes, int n_in,
                              void* d_out, int out_size, void* d_ws, size_t ws_size,
                              hipStream_t stream)
{
  const float* x  = (const float*)d_in[0];
  const float* gm = (const float*)d_in[1];
  const float* bt = (const float*)d_in[2];
  const float* w1 = (const float*)d_in[3];
  const float* b1 = (const float*)d_in[4];
  const float* w2 = (const float*)d_in[5];
  const float* b2 = (const float*)d_in[6];
  const float* w3 = (const float*)d_in[7];
  const float* b3 = (const float*)d_in[8];
  const float* w4 = (const float*)d_in[9];
  const float* b4 = (const float*)d_in[10];
  const float* w5 = (const float*)d_in[11];
  const float* b5 = (const float*)d_in[12];
  const float* w6 = (const float*)d_in[13];
  const float* b6 = (const float*)d_in[14];
  u16* ws  = (u16*)d_ws;
  float* out = (float*)d_out;

  // ws layout (u16 elements)
  const size_t WT_OFF  = 0;          // 1179648
  const size_t N_OFF   = 1179648;    // 2097152
  const size_t T_OFF   = 3276800;    // 3 x 4194304
  const size_t QKV_OFF = 15859712;   // 3 x 4194304
  const size_t NEED_BYTES = 28442624ULL * 2ULL;

  if (ws_size >= NEED_BYTES) {
    prep_k<<<1408, 256, 0, stream>>>(w1, w2, w3, w4, w5, w6, ws + WT_OFF,
                                     x, gm, bt, ws + N_OFF);
    // G1: t_z = act(n @ w{1,3,5} + b{1,3,5})
    gemm_tile<8, 3><<<dim3(64, 4, 3), 512, 0, stream>>>(
        ws + N_OFF, 0, ws + WT_OFF, 0, b1, b3, b5, ws + T_OFF);
    // G2: {Q,K,V}_z = t_z @ w{2,4,6} + b{2,4,6}
    gemm_tile<16, 2><<<dim3(64, 4, 3), 512, 0, stream>>>(
        ws + T_OFF, 4194304, ws + WT_OFF, 131072, b2, b4, b6, ws + QKV_OFF);
    attn_k2<<<512, 512, 0, stream>>>(ws + QKV_OFF, out);
  } else {
    prep_k<<<384, 256, 0, stream>>>(w1, w2, w3, w4, w5, w6, ws + WT_OFF,
                                    x, gm, bt, ws + WT_OFF /*unused*/);
    fused_main<<<256, 1024, 0, stream>>>(x, gm, bt, b1, b2, b3, b4, b5, b6, ws + WT_OFF, out);
  }
}

// Round 9
// 71.414 us; speedup vs baseline: 1.1715x; 1.1715x over previous
//
#include <hip/hip_runtime.h>
#include <hip/hip_bf16.h>

typedef unsigned short u16;
typedef __attribute__((ext_vector_type(8))) unsigned short ushort8;
typedef __attribute__((ext_vector_type(8))) short short8;
typedef __attribute__((ext_vector_type(4))) float f32x4;
typedef __attribute__((ext_vector_type(4))) unsigned uint4_t;

#define DEV __device__ __forceinline__

DEV float b2f(u16 u){ return __uint_as_float(((unsigned)u) << 16); }
DEV u16 f2b(float f){
  unsigned x = __float_as_uint(f);
  return (u16)((x + 0x7fffu + ((x >> 16) & 1u)) >> 16);   // RNE
}
DEV unsigned cvtpk(float lo, float hi){   // HW pack: {bf16(lo), bf16(hi)}
  unsigned r;
  asm("v_cvt_pk_bf16_f32 %0, %1, %2" : "=v"(r) : "v"(lo), "v"(hi));
  return r;
}
// (a,b) -> a={a.lo32,b.lo32}, b={a.hi32,b.hi32}   [lane halves]
DEV void pl32swap(unsigned& a, unsigned& b){
  asm("v_permlane32_swap_b32 %0, %1" : "+v"(a), "+v"(b));
}
// (a,b) -> a[16:31]<->b[0:15], a[48:63]<->b[32:47]
DEV void pl16swap(unsigned& a, unsigned& b){
  asm("v_permlane16_swap_b32 %0, %1" : "+v"(a), "+v"(b));
}
DEV float fexp2(float x){                 // raw 2^x, no libm edge fixup
  float r;
  asm("v_exp_f32 %0, %1" : "=v"(r) : "v"(x));
  return r;
}
DEV float frcp(float x){                  // raw 1/x approx (~1ulp)
  float r;
  asm("v_rcp_f32 %0, %1" : "=v"(r) : "v"(x));
  return r;
}
DEV short8 ld8(const u16* p){ return __builtin_bit_cast(short8, *(const ushort8*)p); }
DEV f32x4 mfma(short8 a, short8 b, f32x4 c){
  return __builtin_amdgcn_mfma_f32_16x16x32_bf16(a, b, c, 0, 0, 0);
}
DEV float fast_tanh(float x){             // tanh = 1 - 2/(e^{2x}+1), 2^: raw exp
  float e = fexp2(x * 2.8853900817779268f);   // 2*log2(e)
  return 1.f - 2.f * frcp(e + 1.f);
}
DEV unsigned pk2(float lo, float hi){
  return (unsigned)f2b(lo) | ((unsigned)f2b(hi) << 16);
}

// ---- prep kernel: blocks 0..383 = weight transpose fp32->bf16; 384..1407 = LN
__global__ __launch_bounds__(256) void prep_k(
    const float* __restrict__ w1, const float* __restrict__ w2,
    const float* __restrict__ w3, const float* __restrict__ w4,
    const float* __restrict__ w5, const float* __restrict__ w6,
    u16* __restrict__ ws,
    const float* __restrict__ xg, const float* __restrict__ gg,
    const float* __restrict__ bgm, u16* __restrict__ ng)
{
  __shared__ u16 tile[64][72];
  const int bid = blockIdx.x;
  if (bid < 384) {
    const int z = bid / 64, rem = bid % 64, by = rem / 8, bx = rem % 8;
    const float* w; u16* wt; int K;
    switch (z) {
      case 0:  w = w1; wt = ws;          K = 256; break;
      case 1:  w = w2; wt = ws + 131072; K = 512; break;
      case 2:  w = w3; wt = ws + 393216; K = 256; break;
      case 3:  w = w4; wt = ws + 524288; K = 512; break;
      case 4:  w = w5; wt = ws + 786432; K = 256; break;
      default: w = w6; wt = ws + 917504; K = 512; break;
    }
    int k0 = by * 64;
    if (k0 >= K) return;                      // uniform per block
    int n0 = bx * 64;
    int t = threadIdx.x;
    int r = t >> 2, c0 = (t & 3) * 16;
    const float* src = w + (size_t)(k0 + r) * 512 + n0 + c0;
    #pragma unroll
    for (int jj = 0; jj < 4; ++jj) {
      float4 v = *(const float4*)(src + jj * 4);
      unsigned* tp = (unsigned*)&tile[r][c0 + jj*4];
      tp[0] = cvtpk(v.x, v.y);
      tp[1] = cvtpk(v.z, v.w);
    }
    __syncthreads();
    ushort8 o0, o1;
    #pragma unroll
    for (int j = 0; j < 8; ++j) { o0[j] = tile[c0 + j][r]; o1[j] = tile[c0 + 8 + j][r]; }
    u16* dst = wt + (size_t)(n0 + r) * K + k0 + c0;
    *(ushort8*)dst       = o0;
    *(ushort8*)(dst + 8) = o1;
  } else {
    const int lb = bid - 384;
    int row = lb * 8 + (threadIdx.x >> 5);
    int l32 = threadIdx.x & 31;
    const float* xr = xg + (size_t)row*256 + l32*8;
    float xf[8];
    #pragma unroll
    for (int j = 0; j < 8; j += 4) {
      float4 v = *(const float4*)(xr + j);
      xf[j] = v.x; xf[j+1] = v.y; xf[j+2] = v.z; xf[j+3] = v.w;
    }
    float s = 0.f, ss = 0.f;
    #pragma unroll
    for (int j = 0; j < 8; ++j){ s += xf[j]; ss += xf[j]*xf[j]; }
    #pragma unroll
    for (int m = 1; m < 32; m <<= 1){ s += __shfl_xor(s, m); ss += __shfl_xor(ss, m); }
    float mean = s * (1.f/256.f);
    float var  = ss * (1.f/256.f) - mean*mean;
    float rs   = rsqrtf(var + 1e-5f);
    float r8[8];
    #pragma unroll
    for (int j = 0; j < 8; j += 4) {
      float4 gv = *(const float4*)(gg  + l32*8 + j);
      float4 bv = *(const float4*)(bgm + l32*8 + j);
      r8[j]   = (xf[j]   - mean)*rs*gv.x + bv.x;
      r8[j+1] = (xf[j+1] - mean)*rs*gv.y + bv.y;
      r8[j+2] = (xf[j+2] - mean)*rs*gv.z + bv.z;
      r8[j+3] = (xf[j+3] - mean)*rs*gv.w + bv.w;
    }
    uint4_t o;
    o[0] = cvtpk(r8[0], r8[1]); o[1] = cvtpk(r8[2], r8[3]);
    o[2] = cvtpk(r8[4], r8[5]); o[3] = cvtpk(r8[6], r8[7]);
    *(uint4_t*)(ng + (size_t)row*256 + l32*8) = o;
  }
}

// ---- batched GEMM: C[8192,512] = act(A[8192,KA] @ Wt[512,KA]^T + bias) ----
// grid (64, 4, 3=z-branch); 512 thr = 8 waves (2M x 4N); tile 128x128, BK=32
template<int NS, int ACT>   // KA = NS*32; ACT: 1 relu, 2 none, 3 per-z (tanh,tanh,relu)
__global__ __launch_bounds__(512, 4) void gemm_tile(
    const u16* __restrict__ Abase, size_t a_zstride,
    const u16* __restrict__ wst, int w_off0,
    const float* __restrict__ bz0, const float* __restrict__ bz1, const float* __restrict__ bz2,
    u16* __restrict__ Cbase)
{
  constexpr int KA = NS * 32;
  __shared__ __align__(16) u16 sm[20480];   // A dbuf [2][5120] | B dbuf [2][5120]; epilogue C-tile [128][132]
  u16* smA = sm;
  u16* smB = sm + 10240;
  const int z = blockIdx.z;
  const u16* A = Abase + (size_t)z * a_zstride;
  const u16* W = wst + w_off0 + z * 393216;
  const float* bias = (z == 0) ? bz0 : ((z == 1) ? bz1 : bz2);
  u16* C = Cbase + (size_t)z * 4194304;
  const int M0 = blockIdx.x * 128, N0 = blockIdx.y * 128;
  const int tid = threadIdx.x;
  const int wv = tid >> 6, ln = tid & 63, q = ln >> 4, r16 = ln & 15;
  const int m0w = (wv >> 2) * 64, n0w = (wv & 3) * 32;
  const f32x4 Z = {0.f, 0.f, 0.f, 0.f};

  // staging: thread -> (row, 8-el chunk)
  const int srow = tid >> 2, scq = (tid & 3) * 8;
  const u16* gA = A + (size_t)(M0 + srow) * KA + scq;
  const u16* gB = W + (size_t)(N0 + srow) * KA + scq;
  u16* dA = smA + srow * 40 + scq;
  u16* dB = smB + srow * 40 + scq;

  ushort8 rA[2], rB[2];
  rA[0] = *(const ushort8*)gA;
  rB[0] = *(const ushort8*)gB;
  *(ushort8*)dA = rA[0];
  *(ushort8*)dB = rB[0];
  if (NS > 1) { rA[1] = *(const ushort8*)(gA + 32); rB[1] = *(const ushort8*)(gB + 32); }
  __syncthreads();

  f32x4 acc[4][2];
  #pragma unroll
  for (int mf = 0; mf < 4; ++mf){ acc[mf][0] = Z; acc[mf][1] = Z; }

  #pragma unroll
  for (int kk = 0; kk < NS; ++kk) {
    const int cur = kk & 1;
    const u16* bufA = smA + cur * 5120;
    const u16* bufB = smB + cur * 5120;
    short8 aF[4], bF[2];
    #pragma unroll
    for (int mf = 0; mf < 4; ++mf) aF[mf] = ld8(bufA + (m0w + mf*16 + r16)*40 + q*8);
    #pragma unroll
    for (int nf = 0; nf < 2; ++nf) bF[nf] = ld8(bufB + (n0w + nf*16 + r16)*40 + q*8);
    #pragma unroll
    for (int mf = 0; mf < 4; ++mf)
      #pragma unroll
      for (int nf = 0; nf < 2; ++nf)
        acc[mf][nf] = mfma(aF[mf], bF[nf], acc[mf][nf]);
    if (kk + 1 < NS) {
      *(ushort8*)(dA + (cur ^ 1) * 5120) = rA[(kk + 1) & 1];
      *(ushort8*)(dB + (cur ^ 1) * 5120) = rB[(kk + 1) & 1];
    }
    if (kk + 2 < NS) {
      rA[kk & 1] = *(const ushort8*)(gA + (kk + 2) * 32);
      rB[kk & 1] = *(const ushort8*)(gB + (kk + 2) * 32);
    }
    __syncthreads();
  }

  // epilogue: bias + act -> LDS C-tile [128][132] -> coalesced global store
  u16* ct = sm;
  #pragma unroll
  for (int nf = 0; nf < 2; ++nf) {
    int colL = n0w + nf*16 + r16;
    float bs = bias[N0 + colL];
    #pragma unroll
    for (int mf = 0; mf < 4; ++mf)
      #pragma unroll
      for (int i = 0; i < 4; ++i) {
        int row = m0w + mf*16 + q*4 + i;
        float v = acc[mf][nf][i] + bs;
        if (ACT == 1) v = fmaxf(v, 0.f);
        else if (ACT == 3) v = (z == 2) ? fmaxf(v, 0.f) : fast_tanh(v);
        ct[row*132 + colL] = f2b(v);
      }
  }
  __syncthreads();
  #pragma unroll
  for (int j = 0; j < 4; ++j) {
    int row = (tid >> 4) + j*32;
    int cb2 = (tid & 15) * 8;
    ushort8 vv = *(const ushort8*)(ct + row*132 + cb2);
    *(ushort8*)(C + (size_t)(M0 + row)*512 + N0 + cb2) = vv;
  }
}

// ---- attention kernel: per-window (grid 256), 1024 thr (R7 structure) ----
// LDS (u16 els):
#define AV   0        // V  [32][520]  (16640)
#define AQT  16640    // Qt [512][40]  (20480)
#define AKT  37120    // Kt [512][40]  (20480)
#define ABT  57600    // beta_time fp32 [32][33] (2112 u16)
#define AAT  59712    // A_time bf16 [32][40] (1280)
#define ASM_ELS 60992

__global__ __launch_bounds__(1024) void attn_k(
    const u16* __restrict__ QKVg, float* __restrict__ outg)
{
  __shared__ __align__(16) u16 sm[ASM_ELS];
  const int tid = threadIdx.x;
  const int bid = blockIdx.x;
  const int wv = tid >> 6, ln = tid & 63, q = ln >> 4, r16 = ln & 15;
  const f32x4 Z = {0.f, 0.f, 0.f, 0.f};
  const float RS512 = 0.04419417382415922f;   // 1/sqrt(512)
  const float C32L2 = 0.25500526676986233f;   // log2(e)/sqrt(32)
  const u16* Qg = QKVg + (size_t)bid * 16384;
  const u16* Kg = QKVg + 4194304 + (size_t)bid * 16384;
  const u16* Vg = QKVg + 8388608 + (size_t)bid * 16384;

  // ---- PX: QK^T (waves 0-3) || Qt build (waves 4-11) || V load (waves 12-15)
  float* btf = (float*)(sm + ABT);
  if (wv < 4) {
    int mt = wv >> 1, nt = wv & 1;
    f32x4 acc = Z;
    const u16* qb = Qg + (mt*16 + r16)*512;
    const u16* kb = Kg + (nt*16 + r16)*512;
    #pragma unroll
    for (int kk = 0; kk < 16; ++kk)
      acc = mfma(ld8(qb + kk*32 + q*8), ld8(kb + kk*32 + q*8), acc);
    #pragma unroll
    for (int i = 0; i < 4; ++i)
      btf[(mt*16 + q*4 + i)*33 + nt*16 + r16] = acc[i] * RS512;
  } else if (wv < 12) {
    int t1 = tid - 256;                  // 0..511
    int rp = t1 & 15;                    // rows 2rp, 2rp+1
    int cb = (t1 >> 4) * 16;             // h-base
    const u16* s0 = Qg + (2*rp)*512 + cb;
    const u16* s1 = s0 + 512;
    ushort8 a0 = *(const ushort8*)s0, a1 = *(const ushort8*)(s0 + 8);
    ushort8 c0v = *(const ushort8*)s1, c1v = *(const ushort8*)(s1 + 8);
    unsigned* qt32 = (unsigned*)(sm + AQT);
    #pragma unroll
    for (int j = 0; j < 8; ++j) {
      qt32[(cb + j)*20 + rp]     = (unsigned)a0[j] | ((unsigned)c0v[j] << 16);
      qt32[(cb + 8 + j)*20 + rp] = (unsigned)a1[j] | ((unsigned)c1v[j] << 16);
    }
  } else {
    int t2 = tid - 768;
    int vrow = t2 >> 3, seg = (t2 & 7) * 64;
    const u16* src = Vg + vrow*512 + seg;
    #pragma unroll
    for (int jj = 0; jj < 8; ++jj)
      *(ushort8*)(sm + AV + vrow*520 + seg + jj*8) = *(const ushort8*)(src + jj*8);
  }
  __syncthreads();

  // ---- PY: time softmax -> A_time (threads 0-511) || Kt build (threads 512-1023)
  if (tid < 512) {
    int row = tid >> 4, v2 = tid & 15;
    float v0 = btf[row*33 + v2], v1 = btf[row*33 + v2 + 16];
    float m = fmaxf(v0, v1);
    #pragma unroll
    for (int msk = 1; msk < 16; msk <<= 1) m = fmaxf(m, __shfl_xor(m, msk));
    float e0 = __expf(v0 - m), e1 = __expf(v1 - m);
    float sum = e0 + e1;
    #pragma unroll
    for (int msk = 1; msk < 16; msk <<= 1) sum += __shfl_xor(sum, msk);
    float inv = 1.f / sum;
    sm[AAT + row*40 + v2]      = f2b(e0 * inv);
    sm[AAT + row*40 + v2 + 16] = f2b(e1 * inv);
  } else {
    int t1 = tid - 512;                  // 0..511
    int rp = t1 & 15;
    int cb = (t1 >> 4) * 16;
    const u16* s0 = Kg + (2*rp)*512 + cb;
    const u16* s1 = s0 + 512;
    ushort8 a0 = *(const ushort8*)s0, a1 = *(const ushort8*)(s0 + 8);
    ushort8 c0v = *(const ushort8*)s1, c1v = *(const ushort8*)(s1 + 8);
    unsigned* kt32 = (unsigned*)(sm + AKT);
    #pragma unroll
    for (int j = 0; j < 8; ++j) {
      kt32[(cb + j)*20 + rp]     = (unsigned)a0[j] | ((unsigned)c0v[j] << 16);
      kt32[(cb + 8 + j)*20 + rp] = (unsigned)a1[j] | ((unsigned)c1v[j] << 16);
    }
  }
  __syncthreads();

  // ---- P6: feature attention (per wave = 32 cols g) + in-register P7 feed
  // E/feat redistributed D-layout -> B-frag layout via permlane swaps
  {
    const int g0 = wv * 32;
    f32x4 facc[2][2];
    facc[0][0]=Z; facc[0][1]=Z; facc[1][0]=Z; facc[1][1]=Z;
    float csum[2] = {0.f, 0.f};
    short8 bK[2];                          // K-dim = w = 32, same frags all tiles
    #pragma unroll
    for (int gt = 0; gt < 2; ++gt)
      bK[gt] = ld8(sm + AKT + (size_t)(g0 + gt*16 + r16)*40 + q*8);

    #pragma unroll 2
    for (int ht = 0; ht < 16; ++ht) {      // h-tiles of 32
      f32x4 sv[2][2];
      #pragma unroll
      for (int smi = 0; smi < 2; ++smi) {
        short8 aQ = ld8(sm + AQT + (ht*32 + smi*16 + r16)*40 + q*8);
        #pragma unroll
        for (int gt = 0; gt < 2; ++gt)
          sv[smi][gt] = mfma(aQ, bK[gt], Z);
      }
      unsigned D[2][4];
      #pragma unroll
      for (int gt = 0; gt < 2; ++gt) {
        float e[2][4];
        #pragma unroll
        for (int smi = 0; smi < 2; ++smi)
          #pragma unroll
          for (int i = 0; i < 4; ++i) {
            float ev = fexp2(sv[smi][gt][i] * C32L2);   // raw v_exp; |logit| small
            e[smi][i] = ev;
            csum[gt] += ev;
          }
        #pragma unroll
        for (int k = 0; k < 2; ++k) {
          unsigned w0 = cvtpk(e[0][2*k], e[0][2*k+1]);  // smi=0 pair
          unsigned w1 = cvtpk(e[1][2*k], e[1][2*k+1]);  // smi=1 pair
          pl32swap(w0, w1);   // w0 = x, w1 = y
          pl16swap(w0, w1);   // w0 = D[k], w1 = D[k+2]
          D[gt][k]     = w0;
          D[gt][k + 2] = w1;
        }
      }
      #pragma unroll
      for (int mt = 0; mt < 2; ++mt) {
        short8 aV = ld8(sm + AV + (mt*16 + r16)*520 + ht*32 + q*8);
        #pragma unroll
        for (int gt = 0; gt < 2; ++gt) {
          uint4_t dv = {D[gt][0], D[gt][1], D[gt][2], D[gt][3]};
          short8 bE = __builtin_bit_cast(short8, dv);
          facc[mt][gt] = mfma(aV, bE, facc[mt][gt]);
        }
      }
    }
    float inv[2];
    #pragma unroll
    for (int gt = 0; gt < 2; ++gt) {
      float cs = csum[gt];
      cs += __shfl_xor(cs, 16);
      cs += __shfl_xor(cs, 32);
      inv[gt] = 1.f / cs;
    }
    // normalize + redistribute facc (D-layout) -> B-frag layout via permlane
    unsigned F[2][4];
    #pragma unroll
    for (int gt = 0; gt < 2; ++gt) {
      float e0n[4], e1n[4];
      #pragma unroll
      for (int i = 0; i < 4; ++i) {
        e0n[i] = facc[0][gt][i] * inv[gt];
        e1n[i] = facc[1][gt][i] * inv[gt];
      }
      #pragma unroll
      for (int k = 0; k < 2; ++k) {
        unsigned w0 = cvtpk(e0n[2*k], e0n[2*k+1]);      // mt=0 pair
        unsigned w1 = cvtpk(e1n[2*k], e1n[2*k+1]);      // mt=1 pair
        pl32swap(w0, w1);
        pl16swap(w0, w1);
        F[gt][k]     = w0;
        F[gt][k + 2] = w1;
      }
    }
    // ---- P7: out = A_time @ feat (feat fed from registers) ----
    short8 aA0 = ld8(sm + AAT + r16*40 + q*8);
    short8 aA1 = ld8(sm + AAT + (16 + r16)*40 + q*8);
    #pragma unroll
    for (int gt = 0; gt < 2; ++gt) {
      uint4_t fv = {F[gt][0], F[gt][1], F[gt][2], F[gt][3]};
      short8 bF = __builtin_bit_cast(short8, fv);
      f32x4 o0 = mfma(aA0, bF, Z);
      f32x4 o1 = mfma(aA1, bF, Z);
      #pragma unroll
      for (int i = 0; i < 4; ++i) {
        int g = g0 + gt*16 + r16;
        outg[(size_t)(bid*32 + q*4 + i)*512 + g]      = o0[i];
        outg[(size_t)(bid*32 + 16 + q*4 + i)*512 + g] = o1[i];
      }
    }
  }
}

// =================== FALLBACK (R4 mega-kernel, unchanged) ===================

#define OFF_V   0
#define OFF_N   16640
#define OFF_T   25088
#define OFF_Q   41728
#define OFF_K   58368
#define OFF_BT  75008
#define OFF_QT  16640
#define OFF_KT  37120
#define OFF_AT  78080
#define OFF_FT  37120
#define SMEM_ELS 79360

template<int ACT>
DEV void mlp_branch(const u16* __restrict__ nl, u16* __restrict__ tl, u16* __restrict__ ol,
                    const u16* __restrict__ wA, const float* __restrict__ bA,
                    const u16* __restrict__ wB, const float* __restrict__ bB,
                    int wv, int q, int r16)
{
  const f32x4 Z = {0.f, 0.f, 0.f, 0.f};
  const int c0 = wv*32 + r16;
  float biasA0 = bA[c0], biasA1 = bA[c0 + 16];
  float biasB0 = bB[c0], biasB1 = bB[c0 + 16];
  {
    const u16* cp0 = wA + (size_t)c0*256 + q*8;
    const u16* cp1 = cp0 + 16*256;
    const u16* a0p = nl + r16 * 264 + q*8;
    const u16* a1p = nl + (16 + r16) * 264 + q*8;
    f32x4 acc[2][2];
    acc[0][0]=Z; acc[0][1]=Z; acc[1][0]=Z; acc[1][1]=Z;
    #pragma unroll
    for (int kk = 0; kk < 8; ++kk) {
      short8 a0 = ld8(a0p + kk*32);
      short8 a1 = ld8(a1p + kk*32);
      short8 b0 = ld8(cp0 + kk*32);
      short8 b1 = ld8(cp1 + kk*32);
      acc[0][0] = mfma(a0, b0, acc[0][0]);
      acc[1][0] = mfma(a1, b0, acc[1][0]);
      acc[0][1] = mfma(a0, b1, acc[0][1]);
      acc[1][1] = mfma(a1, b1, acc[1][1]);
    }
    #pragma unroll
    for (int gt = 0; gt < 2; ++gt) {
      float bias = gt ? biasA1 : biasA0;
      #pragma unroll
      for (int mt = 0; mt < 2; ++mt)
        #pragma unroll
        for (int i = 0; i < 4; ++i) {
          float v = acc[mt][gt][i] + bias;
          v = (ACT == 0) ? fast_tanh(v) : fmaxf(v, 0.f);
          tl[(mt*16 + q*4 + i)*520 + c0 + gt*16] = f2b(v);
        }
    }
  }
  __syncthreads();
  {
    const u16* cp0 = wB + (size_t)c0*512 + q*8;
    const u16* cp1 = cp0 + 16*512;
    const u16* a0p = tl + r16 * 520 + q*8;
    const u16* a1p = tl + (16 + r16) * 520 + q*8;
    f32x4 acc[2][2];
    acc[0][0]=Z; acc[0][1]=Z; acc[1][0]=Z; acc[1][1]=Z;
    #pragma unroll
    for (int kk = 0; kk < 16; ++kk) {
      short8 a0 = ld8(a0p + kk*32);
      short8 a1 = ld8(a1p + kk*32);
      short8 b0 = ld8(cp0 + kk*32);
      short8 b1 = ld8(cp1 + kk*32);
      acc[0][0] = mfma(a0, b0, acc[0][0]);
      acc[1][0] = mfma(a1, b0, acc[1][0]);
      acc[0][1] = mfma(a0, b1, acc[0][1]);
      acc[1][1] = mfma(a1, b1, acc[1][1]);
    }
    #pragma unroll
    for (int gt = 0; gt < 2; ++gt) {
      float bias = gt ? biasB1 : biasB0;
      #pragma unroll
      for (int mt = 0; mt < 2; ++mt)
        #pragma unroll
        for (int i = 0; i < 4; ++i)
          ol[(mt*16 + q*4 + i)*520 + c0 + gt*16] = f2b(acc[mt][gt][i] + bias);
    }
  }
}

__global__ __launch_bounds__(1024) void fused_main(
    const float* __restrict__ xg, const float* __restrict__ gg, const float* __restrict__ bgm,
    const float* __restrict__ b1, const float* __restrict__ b2, const float* __restrict__ b3,
    const float* __restrict__ b4, const float* __restrict__ b5, const float* __restrict__ b6,
    const u16* __restrict__ wst, float* __restrict__ outg)
{
  __shared__ __align__(16) u16 sm[SMEM_ELS];
  const int tid = threadIdx.x;
  const int bid = blockIdx.x;
  const int wv = tid >> 6, ln = tid & 63, q = ln >> 4, r16 = ln & 15;
  const f32x4 Z = {0.f, 0.f, 0.f, 0.f};
  const float RS512 = 0.04419417382415922f;
  const float C32L2 = 0.25500526676986233f;

  {
    int row = tid >> 5, l32 = tid & 31;
    const float* xr = xg + (size_t)(bid*32 + row)*256 + l32*8;
    float xf[8];
    #pragma unroll
    for (int j = 0; j < 8; j += 4) {
      float4 v = *(const float4*)(xr + j);
      xf[j] = v.x; xf[j+1] = v.y; xf[j+2] = v.z; xf[j+3] = v.w;
    }
    float s = 0.f, ss = 0.f;
    #pragma unroll
    for (int j = 0; j < 8; ++j){ s += xf[j]; ss += xf[j]*xf[j]; }
    #pragma unroll
    for (int m = 1; m < 32; m <<= 1){ s += __shfl_xor(s, m); ss += __shfl_xor(ss, m); }
    float mean = s * (1.f/256.f);
    float var  = ss * (1.f/256.f) - mean*mean;
    float rs   = rsqrtf(var + 1e-5f);
    float gf[8], bf[8];
    #pragma unroll
    for (int j = 0; j < 8; j += 4) {
      float4 gv = *(const float4*)(gg  + l32*8 + j);
      float4 bv = *(const float4*)(bgm + l32*8 + j);
      gf[j] = gv.x; gf[j+1] = gv.y; gf[j+2] = gv.z; gf[j+3] = gv.w;
      bf[j] = bv.x; bf[j+1] = bv.y; bf[j+2] = bv.z; bf[j+3] = bv.w;
    }
    ushort8 o0;
    #pragma unroll
    for (int j = 0; j < 8; ++j)
      o0[j] = f2b((xf[j] - mean)*rs*gf[j] + bf[j]);
    *(ushort8*)(sm + OFF_N + row*264 + l32*8) = o0;
  }
  __syncthreads();

  mlp_branch<0>(sm+OFF_N, sm+OFF_T, sm+OFF_Q, wst,          b1, wst + 131072, b2, wv, q, r16);
  __syncthreads();
  mlp_branch<0>(sm+OFF_N, sm+OFF_T, sm+OFF_K, wst + 393216, b3, wst + 524288, b4, wv, q, r16);
  __syncthreads();
  mlp_branch<1>(sm+OFF_N, sm+OFF_T, sm+OFF_V, wst + 786432, b5, wst + 917504, b6, wv, q, r16);
  __syncthreads();

  float* btf = (float*)(sm + OFF_BT);
  if (wv < 4) {
    int mt = wv >> 1, nt = wv & 1;
    f32x4 acc = Z;
    const u16* qb = sm + OFF_Q + (mt*16 + r16)*520;
    const u16* kb = sm + OFF_K + (nt*16 + r16)*520;
    for (int kk = 0; kk < 16; ++kk)
      acc = mfma(ld8(qb + kk*32 + q*8), ld8(kb + kk*32 + q*8), acc);
    #pragma unroll
    for (int i = 0; i < 4; ++i)
      btf[(mt*16 + q*4 + i)*33 + nt*16 + r16] = acc[i] * RS512;
  } else if (wv < 12) {
    int t1 = tid - 256;
    int row = t1 & 31, cb = (t1 >> 5) * 32;
    const u16* src = sm + OFF_Q + row*520 + cb;
    ushort8 v[4];
    #pragma unroll
    for (int jj = 0; jj < 4; ++jj) v[jj] = *(const ushort8*)(src + jj*8);
    #pragma unroll
    for (int jj = 0; jj < 4; ++jj)
      #pragma unroll
      for (int j = 0; j < 8; ++j)
        sm[OFF_QT + (cb + jj*8 + j)*40 + row] = v[jj][j];
  }
  __syncthreads();

  if (tid < 512) {
    int row = tid >> 4, v2 = tid & 15;
    float v0 = btf[row*33 + v2], v1 = btf[row*33 + v2 + 16];
    float m = fmaxf(v0, v1);
    #pragma unroll
    for (int msk = 1; msk < 16; msk <<= 1) m = fmaxf(m, __shfl_xor(m, msk));
    float e0 = __expf(v0 - m), e1 = __expf(v1 - m);
    float sum = e0 + e1;
    #pragma unroll
    for (int msk = 1; msk < 16; msk <<= 1) sum += __shfl_xor(sum, msk);
    float inv = 1.f / sum;
    sm[OFF_AT + row*40 + v2]      = f2b(e0 * inv);
    sm[OFF_AT + row*40 + v2 + 16] = f2b(e1 * inv);
  } else {
    int t2 = tid - 512;
    int row = t2 & 31, cb = (t2 >> 5) * 32;
    const u16* src = sm + OFF_K + row*520 + cb;
    ushort8 v[4];
    #pragma unroll
    for (int jj = 0; jj < 4; ++jj) v[jj] = *(const ushort8*)(src + jj*8);
    #pragma unroll
    for (int jj = 0; jj < 4; ++jj)
      #pragma unroll
      for (int j = 0; j < 8; ++j)
        sm[OFF_KT + (cb + jj*8 + j)*40 + row] = v[jj][j];
  }
  __syncthreads();

  {
    const int g0 = wv * 32;
    const bool hi32 = (ln >= 32);
    const bool qodd = (q & 1);
    f32x4 facc[2][2];
    facc[0][0]=Z; facc[0][1]=Z; facc[1][0]=Z; facc[1][1]=Z;
    float csum[2] = {0.f, 0.f};
    short8 bK[2];
    #pragma unroll
    for (int gt = 0; gt < 2; ++gt)
      bK[gt] = ld8(sm + OFF_KT + (size_t)(g0 + gt*16 + r16)*40 + q*8);

    #pragma unroll 2
    for (int ht = 0; ht < 16; ++ht) {
      f32x4 sv[2][2];
      #pragma unroll
      for (int smi = 0; smi < 2; ++smi) {
        short8 aQ = ld8(sm + OFF_QT + (ht*32 + smi*16 + r16)*40 + q*8);
        #pragma unroll
        for (int gt = 0; gt < 2; ++gt)
          sv[smi][gt] = mfma(aQ, bK[gt], Z);
      }
      unsigned D[2][4];
      #pragma unroll
      for (int gt = 0; gt < 2; ++gt) {
        float e[2][4];
        #pragma unroll
        for (int smi = 0; smi < 2; ++smi)
          #pragma unroll
          for (int i = 0; i < 4; ++i) {
            float ev = fexp2(sv[smi][gt][i] * C32L2);
            e[smi][i] = ev;
            csum[gt] += ev;
          }
        #pragma unroll
        for (int k = 0; k < 2; ++k) {
          unsigned w0 = pk2(e[0][2*k], e[0][2*k+1]);
          unsigned w1 = pk2(e[1][2*k], e[1][2*k+1]);
          unsigned Pw0 = (unsigned)__shfl_xor((int)w0, 32);
          unsigned Pw1 = (unsigned)__shfl_xor((int)w1, 32);
          unsigned x = hi32 ? Pw1 : w0;
          unsigned y = hi32 ? w1 : Pw0;
          unsigned xs = (unsigned)__shfl_xor((int)x, 16);
          unsigned ys = (unsigned)__shfl_xor((int)y, 16);
          D[gt][k]     = qodd ? ys : x;
          D[gt][k + 2] = qodd ? y  : xs;
        }
      }
      #pragma unroll
      for (int mt = 0; mt < 2; ++mt) {
        short8 aV = ld8(sm + OFF_V + (mt*16 + r16)*520 + ht*32 + q*8);
        #pragma unroll
        for (int gt = 0; gt < 2; ++gt) {
          uint4_t dv = {D[gt][0], D[gt][1], D[gt][2], D[gt][3]};
          short8 bE = __builtin_bit_cast(short8, dv);
          facc[mt][gt] = mfma(aV, bE, facc[mt][gt]);
        }
      }
    }
    float inv[2];
    #pragma unroll
    for (int gt = 0; gt < 2; ++gt) {
      float cs = csum[gt];
      cs += __shfl_xor(cs, 16);
      cs += __shfl_xor(cs, 32);
      inv[gt] = 1.f / cs;
    }
    #pragma unroll
    for (int mt = 0; mt < 2; ++mt)
      #pragma unroll
      for (int gt = 0; gt < 2; ++gt)
        #pragma unroll
        for (int i = 0; i < 4; ++i) {
          int w = mt*16 + q*4 + i;
          int g = g0 + gt*16 + r16;
          sm[OFF_FT + g*40 + w] = f2b(facc[mt][gt][i] * inv[gt]);
        }
  }

  {
    const int g0 = wv * 32;
    short8 aA0 = ld8(sm + OFF_AT + r16*40 + q*8);
    short8 aA1 = ld8(sm + OFF_AT + (16 + r16)*40 + q*8);
    #pragma unroll
    for (int gt = 0; gt < 2; ++gt) {
      short8 bF = ld8(sm + OFF_FT + (size_t)(g0 + gt*16 + r16)*40 + q*8);
      f32x4 o0 = mfma(aA0, bF, Z);
      f32x4 o1 = mfma(aA1, bF, Z);
      #pragma unroll
      for (int i = 0; i < 4; ++i) {
        int g = g0 + gt*16 + r16;
        outg[(size_t)(bid*32 + q*4 + i)*512 + g]      = o0[i];
        outg[(size_t)(bid*32 + 16 + q*4 + i)*512 + g] = o1[i];
      }
    }
  }
}

// =================== launch ===================

extern "C" void kernel_launch(void* const* d_in, const int* in_sizes, int n_in,
                              void* d_out, int out_size, void* d_ws, size_t ws_size,
                              hipStream_t stream)
{
  const float* x  = (const float*)d_in[0];
  const float* gm = (const float*)d_in[1];
  const float* bt = (const float*)d_in[2];
  const float* w1 = (const float*)d_in[3];
  const float* b1 = (const float*)d_in[4];
  const float* w2 = (const float*)d_in[5];
  const float* b2 = (const float*)d_in[6];
  const float* w3 = (const float*)d_in[7];
  const float* b3 = (const float*)d_in[8];
  const float* w4 = (const float*)d_in[9];
  const float* b4 = (const float*)d_in[10];
  const float* w5 = (const float*)d_in[11];
  const float* b5 = (const float*)d_in[12];
  const float* w6 = (const float*)d_in[13];
  const float* b6 = (const float*)d_in[14];
  u16* ws  = (u16*)d_ws;
  float* out = (float*)d_out;

  // ws layout (u16 elements)
  const size_t WT_OFF  = 0;          // 1179648
  const size_t N_OFF   = 1179648;    // 2097152
  const size_t T_OFF   = 3276800;    // 3 x 4194304
  const size_t QKV_OFF = 15859712;   // 3 x 4194304
  const size_t NEED_BYTES = 28442624ULL * 2ULL;

  if (ws_size >= NEED_BYTES) {
    prep_k<<<1408, 256, 0, stream>>>(w1, w2, w3, w4, w5, w6, ws + WT_OFF,
                                     x, gm, bt, ws + N_OFF);
    // G1: t_z = act(n @ w{1,3,5} + b{1,3,5})
    gemm_tile<8, 3><<<dim3(64, 4, 3), 512, 0, stream>>>(
        ws + N_OFF, 0, ws + WT_OFF, 0, b1, b3, b5, ws + T_OFF);
    // G2: {Q,K,V}_z = t_z @ w{2,4,6} + b{2,4,6}
    gemm_tile<16, 2><<<dim3(64, 4, 3), 512, 0, stream>>>(
        ws + T_OFF, 4194304, ws + WT_OFF, 131072, b2, b4, b6, ws + QKV_OFF);
    attn_k<<<256, 1024, 0, stream>>>(ws + QKV_OFF, out);
  } else {
    prep_k<<<384, 256, 0, stream>>>(w1, w2, w3, w4, w5, w6, ws + WT_OFF,
                                    x, gm, bt, ws + WT_OFF /*unused*/);
    fused_main<<<256, 1024, 0, stream>>>(x, gm, bt, b1, b2, b3, b4, b5, b6, ws + WT_OFF, out);
  }
}